// Round 7
// baseline (575.715 us; speedup 1.0000x reference)
//
#include <hip/hip_runtime.h>

// GCN 2-layer + head.
// R7: CSR rows sorted by src (per-bin LDS bitonic on dst-major keys) so the
//     ~8192 resident row-waves sweep src-space in lockstep -> L2-resident
//     gather window. Build remains zero-global-atomic.
// bucket word = (src<<7)|(dst&127); sort key = (dstlocal<<17)|src (24 bits).

#define HID 64
#define INC 11
#define BINSH 7
#define BINW 128
#define MAXNB 800      // >= ceil(100000/128)=782
#define ECHUNK 16384
#define SCAN_CHUNK 1024
#define SORT_MAX 8192  // per-bin sort capacity (32 KB LDS)

// ---- per-chunk histogram of dst bins, stored transposed histT[b*C+c] ----
__global__ void k_hist(const int* __restrict__ dst, int E, int C, int NB,
                       int* __restrict__ histT) {
    __shared__ int h[MAXNB];
    int c = blockIdx.x, t = threadIdx.x;
    for (int i = t; i < NB; i += 256) h[i] = 0;
    __syncthreads();
    int base = c * ECHUNK;
    int end = min(base + ECHUNK, E);
    for (int i = base + t; i < end; i += 256)
        atomicAdd(&h[dst[i] >> BINSH], 1);
    __syncthreads();
    for (int b = t; b < NB; b += 256)
        histT[(size_t)b * C + c] = h[b];
}

// ---- generic 3-kernel exclusive scan (in-place safe), L <= 256*SCAN_CHUNK ----
__global__ void k_scan1(const int* __restrict__ in, int L,
                        int* __restrict__ part, int* __restrict__ blocksums) {
    __shared__ int lds[SCAN_CHUNK];
    __shared__ int tsum[256];
    int b = blockIdx.x, t = threadIdx.x;
    int base = b * SCAN_CHUNK;
    for (int i = t; i < SCAN_CHUNK; i += 256)
        lds[i] = (base + i < L) ? in[base + i] : 0;
    __syncthreads();
    int a0 = lds[t*4], a1 = lds[t*4+1], a2 = lds[t*4+2], a3 = lds[t*4+3];
    int ts = a0 + a1 + a2 + a3;
    tsum[t] = ts;
    __syncthreads();
    for (int off = 1; off < 256; off <<= 1) {
        int v = (t >= off) ? tsum[t - off] : 0;
        __syncthreads();
        tsum[t] += v;
        __syncthreads();
    }
    int excl = tsum[t] - ts;
    int i0 = base + t*4;
    if (i0     < L) part[i0]     = excl;
    if (i0 + 1 < L) part[i0 + 1] = excl + a0;
    if (i0 + 2 < L) part[i0 + 2] = excl + a0 + a1;
    if (i0 + 3 < L) part[i0 + 3] = excl + a0 + a1 + a2;
    if (t == 255) blocksums[b] = tsum[255];
}

__global__ void k_scan2(const int* __restrict__ blocksums, int nb, int* __restrict__ blockoff) {
    __shared__ int s[256];
    int t = threadIdx.x;
    s[t] = (t < nb) ? blocksums[t] : 0;
    __syncthreads();
    int mine = s[t];
    for (int off = 1; off < 256; off <<= 1) {
        int v = (t >= off) ? s[t - off] : 0;
        __syncthreads();
        s[t] += v;
        __syncthreads();
    }
    blockoff[t] = s[t] - mine;   // exclusive
}

__global__ void k_scan3f(int* __restrict__ part, const int* __restrict__ blockoff, int L) {
    int i = blockIdx.x * blockDim.x + threadIdx.x;
    if (i < L) part[i] += blockoff[i / SCAN_CHUNK];
}

// ---- scatter edges into bin-grouped bucket; rank via LDS atomic ----
__global__ void k_scatterbin(const int* __restrict__ src, const int* __restrict__ dst,
                             int E, int C, int NB, const int* __restrict__ scanT,
                             int* __restrict__ bucket) {
    __shared__ int cur[MAXNB];
    int c = blockIdx.x, t = threadIdx.x;
    for (int b = t; b < NB; b += 256) cur[b] = scanT[(size_t)b * C + c];
    __syncthreads();
    int base = c * ECHUNK;
    int end = min(base + ECHUNK, E);
    for (int i = base + t; i < end; i += 1024) {
        int i1 = i + 256, i2 = i + 512, i3 = i + 768;
        int d0 = dst[i];
        int d1 = (i1 < end) ? dst[i1] : -1;
        int d2 = (i2 < end) ? dst[i2] : -1;
        int d3 = (i3 < end) ? dst[i3] : -1;
        int s0 = src[i];
        int s1 = (i1 < end) ? src[i1] : 0;
        int s2 = (i2 < end) ? src[i2] : 0;
        int s3 = (i3 < end) ? src[i3] : 0;
        int r0 = atomicAdd(&cur[d0 >> BINSH], 1);
        int r1 = (d1 >= 0) ? atomicAdd(&cur[d1 >> BINSH], 1) : 0;
        int r2 = (d2 >= 0) ? atomicAdd(&cur[d2 >> BINSH], 1) : 0;
        int r3 = (d3 >= 0) ? atomicAdd(&cur[d3 >> BINSH], 1) : 0;
        bucket[r0] = (s0 << BINSH) | (d0 & (BINW - 1));
        if (d1 >= 0) bucket[r1] = (s1 << BINSH) | (d1 & (BINW - 1));
        if (d2 >= 0) bucket[r2] = (s2 << BINSH) | (d2 & (BINW - 1));
        if (d3 >= 0) bucket[r3] = (s3 << BINSH) | (d3 & (BINW - 1));
    }
}

// ---- per-bin CSR finalize: histogram -> rowptr/dis; LDS bitonic sort on
//      dst-major keys -> csr rows in order, each row ascending in src. ----
__global__ __launch_bounds__(512)
void k_csrsort(const int* __restrict__ scanT, int C, int NB, int E,
               const int* __restrict__ bucket, int* __restrict__ csr,
               int* __restrict__ rowptr, float* __restrict__ dis, int N) {
    __shared__ int cnt[BINW];
    __shared__ int ex[BINW];
    __shared__ int cur[BINW];
    __shared__ int q[SORT_MAX];   // 32 KB
    int b = blockIdx.x, t = threadIdx.x;     // 512 threads
    int s = scanT[(size_t)b * C];
    int e = (b + 1 < NB) ? scanT[(size_t)(b + 1) * C] : E;
    int len = e - s;
    if (t < BINW) cnt[t] = 0;
    __syncthreads();
    bool sortable = (len <= SORT_MAX);
    if (sortable) {
        for (int i = t; i < len; i += 512) {
            int w = bucket[s + i];
            int dl = w & (BINW - 1);
            q[i] = (dl << 17) | (w >> BINSH);
            atomicAdd(&cnt[dl], 1);
        }
    } else {
        for (int i = t; i < len; i += 512)
            atomicAdd(&cnt[bucket[s + i] & (BINW - 1)], 1);
    }
    __syncthreads();
    // inclusive scan of cnt over 128 entries
    if (t < BINW) ex[t] = cnt[t];
    __syncthreads();
    for (int off = 1; off < BINW; off <<= 1) {
        int v = (t < BINW && t >= off) ? ex[t - off] : 0;
        __syncthreads();
        if (t < BINW) ex[t] += v;
        __syncthreads();
    }
    if (t < BINW) {
        int excl = ex[t] - cnt[t];
        cur[t] = excl;
        int n = b * BINW + t;
        if (n <= N) rowptr[n] = s + excl;    // rowptr[N]=E lands here in last bin
        if (n < N)  dis[n] = rsqrtf((float)(cnt[t] + 1));
    }
    __syncthreads();
    if (sortable) {
        int npow = 1;
        while (npow < len) npow <<= 1;
        if (npow < 2) npow = 2;
        for (int i = len + t; i < npow; i += 512) q[i] = 0x7FFFFFFF;
        __syncthreads();
        for (int k = 2; k <= npow; k <<= 1) {
            for (int j = k >> 1; j > 0; j >>= 1) {
                for (int i = t; i < npow; i += 512) {
                    int l = i ^ j;
                    if (l > i) {
                        int a = q[i], c2 = q[l];
                        bool up = ((i & k) == 0);
                        if ((a > c2) == up) { q[i] = c2; q[l] = a; }
                    }
                }
                __syncthreads();
            }
        }
        for (int i = t; i < len; i += 512)
            csr[s + i] = q[i] & 0x1FFFF;
    } else {
        // fallback: unsorted rank-scatter (correct, just less cache-friendly)
        for (int p = s + t; p < e; p += 512) {
            int w = bucket[p];
            int r = atomicAdd(&cur[w & (BINW - 1)], 1);
            csr[s + r] = w >> BINSH;
        }
    }
}

// ---- g[N,64] = dis[row] * (x[N,11] @ W1[11,64]) ----
__global__ void k_xw1(const float* __restrict__ x, const float* __restrict__ W1,
                      const float* __restrict__ dis, float* __restrict__ g, int N) {
    __shared__ float Ws[INC * HID];
    int t = threadIdx.x;
    for (int i = t; i < INC * HID; i += blockDim.x) Ws[i] = W1[i];
    __syncthreads();
    int c = t & 63;
    for (int row = blockIdx.x * 4 + (t >> 6); row < N; row += gridDim.x * 4) {
        float acc = 0.f;
        #pragma unroll
        for (int k = 0; k < INC; ++k) acc += x[row * INC + k] * Ws[k * HID + c];
        g[row * HID + c] = dis[row] * acc;
    }
}

// ---- g2[N,64] = dis[row] * (a[N,64] @ W2[64,64]), persistent blocks ----
__global__ void k_xw2(const float* __restrict__ in, const float* __restrict__ W2,
                      const float* __restrict__ dis, float* __restrict__ g, int N) {
    __shared__ float Ws[HID * HID];
    int t = threadIdx.x;
    for (int i = t; i < HID * HID; i += blockDim.x) Ws[i] = W2[i];
    __syncthreads();
    int c = t & 63;
    for (int row = blockIdx.x * 4 + (t >> 6); row < N; row += gridDim.x * 4) {
        const float* r = in + row * HID;
        float acc = 0.f;
        #pragma unroll
        for (int k = 0; k < HID; k += 4) {
            float4 rv = *(const float4*)(r + k);
            acc += rv.x * Ws[(k    ) * HID + c];
            acc += rv.y * Ws[(k + 1) * HID + c];
            acc += rv.z * Ws[(k + 2) * HID + c];
            acc += rv.w * Ws[(k + 3) * HID + c];
        }
        g[row * HID + c] = dis[row] * acc;
    }
}

// ---- neighbor-sum core, 4 gathers in flight ----
__device__ __forceinline__ float agg_row(const int* __restrict__ rowptr,
                                         const int* __restrict__ csr,
                                         const float* __restrict__ g,
                                         int row, int lane) {
    int s = rowptr[row], e = rowptr[row + 1];
    float acc = g[(size_t)row * HID + lane];   // self-loop (dis folded in g)
    for (int p = s; p < e; p += 64) {
        int idx = (p + lane < e) ? csr[p + lane] : 0;
        int cnt = min(64, e - p);
        int j = 0;
        for (; j + 3 < cnt; j += 4) {
            int s0 = __shfl(idx, j);
            int s1 = __shfl(idx, j + 1);
            int s2 = __shfl(idx, j + 2);
            int s3 = __shfl(idx, j + 3);
            float v0 = g[(size_t)s0 * HID + lane];
            float v1 = g[(size_t)s1 * HID + lane];
            float v2 = g[(size_t)s2 * HID + lane];
            float v3 = g[(size_t)s3 * HID + lane];
            acc += v0; acc += v1; acc += v2; acc += v3;
        }
        for (; j < cnt; ++j)
            acc += g[(size_t)__shfl(idx, j) * HID + lane];
    }
    return acc;
}

// ---- layer-1 aggregation: a[row] = relu(dis[row]*sum + b) ----
__global__ void k_agg1(const int* __restrict__ rowptr, const int* __restrict__ csr,
                       const float* __restrict__ g, const float* __restrict__ dis,
                       const float* __restrict__ b, float* __restrict__ outA, int N) {
    int lane = threadIdx.x & 63;
    int row = (blockIdx.x * blockDim.x + threadIdx.x) >> 6;
    if (row >= N) return;
    float acc = agg_row(rowptr, csr, g, row, lane);
    float v = dis[row] * acc + b[lane];
    outA[(size_t)row * HID + lane] = v > 0.f ? v : 0.f;
}

// ---- layer-2 aggregation fused with head ----
__global__ void k_agg2_head(const int* __restrict__ rowptr, const int* __restrict__ csr,
                            const float* __restrict__ g, const float* __restrict__ dis,
                            const float* __restrict__ b, const float* __restrict__ Wl,
                            const float* __restrict__ bl, float* __restrict__ out, int N) {
    int lane = threadIdx.x & 63;
    int row = (blockIdx.x * blockDim.x + threadIdx.x) >> 6;
    if (row >= N) return;
    float acc = agg_row(rowptr, csr, g, row, lane);
    float v = dis[row] * acc + b[lane];
    v = v > 0.f ? v : 0.f;
    v *= Wl[lane];
    #pragma unroll
    for (int off = 32; off > 0; off >>= 1) v += __shfl_down(v, off);
    if (lane == 0) out[row] = v + bl[0];
}

extern "C" void kernel_launch(void* const* d_in, const int* in_sizes, int n_in,
                              void* d_out, int out_size, void* d_ws, size_t ws_size,
                              hipStream_t stream) {
    const float* x  = (const float*)d_in[0];
    const int*   ei = (const int*)d_in[1];
    const float* W1 = (const float*)d_in[2];
    const float* b1 = (const float*)d_in[3];
    const float* W2 = (const float*)d_in[4];
    const float* b2 = (const float*)d_in[5];
    const float* Wl = (const float*)d_in[6];
    const float* bl = (const float*)d_in[7];
    float* out = (float*)d_out;

    const int N = in_sizes[0] / INC;    // 100000
    const int E = in_sizes[1] / 2;      // 3200000
    const int NB = (N + BINW - 1) / BINW;        // 782
    const int C  = (E + ECHUNK - 1) / ECHUNK;    // 196
    const int L  = NB * C;                        // 153272
    const int nScan = (L + SCAN_CHUNK - 1) / SCAN_CHUNK;  // 150 (<=256)

    char* ws = (char*)d_ws;
    size_t off = 0;
    auto alloc = [&](size_t bytes) { void* p = ws + off; off += (bytes + 255) / 256 * 256; return p; };
    int*   histT    = (int*)alloc((size_t)L * 4);     // scanned in place
    int*   blocksums= (int*)alloc(256 * 4);
    int*   blockoff = (int*)alloc(256 * 4);
    int*   rowptr   = (int*)alloc((size_t)(N + 1) * 4);
    float* dis      = (float*)alloc((size_t)N * 4);
    int*   csr      = (int*)alloc((size_t)E * 4);
    float* bufG     = (float*)alloc((size_t)N * HID * 4);
    float* bufA     = (float*)alloc((size_t)N * HID * 4);
    // bucket (E ints = 12.8 MB) aliases bufA: bucket's last read (k_csrsort)
    // precedes bufA's first write (k_agg1).
    int* bucket = (int*)bufA;

    const int TPB = 256;
    const int* esrc = ei;
    const int* edst = ei + E;
    const int waveBlocks = ((size_t)N * 64 + TPB - 1) / TPB;   // wave per row

    // CSR build — zero global atomics, rows src-sorted
    k_hist<<<C, TPB, 0, stream>>>(edst, E, C, NB, histT);
    k_scan1<<<nScan, TPB, 0, stream>>>(histT, L, histT, blocksums);
    k_scan2<<<1, TPB, 0, stream>>>(blocksums, nScan, blockoff);
    k_scan3f<<<(L + TPB - 1) / TPB, TPB, 0, stream>>>(histT, blockoff, L);
    k_scatterbin<<<C, TPB, 0, stream>>>(esrc, edst, E, C, NB, histT, bucket);
    k_csrsort<<<NB, 512, 0, stream>>>(histT, C, NB, E, bucket, csr, rowptr, dis, N);

    // layer 1
    k_xw1<<<2048, TPB, 0, stream>>>(x, W1, dis, bufG, N);
    k_agg1<<<waveBlocks, TPB, 0, stream>>>(rowptr, csr, bufG, dis, b1, bufA, N);

    // layer 2 (+ fused head)
    k_xw2<<<2048, TPB, 0, stream>>>(bufA, W2, dis, bufG, N);
    k_agg2_head<<<waveBlocks, TPB, 0, stream>>>(rowptr, csr, bufG, dis, b2, Wl, bl, out, N);
}

// Round 8
// 352.591 us; speedup vs baseline: 1.6328x; 1.6328x over previous
//
#include <hip/hip_runtime.h>

// GCN 2-layer + head.
// R8: R6 structure (atomic-free binned CSR build + wave-per-row CSR agg),
//     sort reverted (R7 falsified the lockstep-locality theory),
//     agg gather MLP deepened 4 -> 8 outstanding loads per wave.
// bucket word = (src<<7) | (dst&127), src < 2^17 so fits in 24 bits.

#define HID 64
#define INC 11
#define BINSH 7
#define BINW 128
#define MAXNB 800      // >= ceil(100000/128)=782
#define ECHUNK 16384
#define SCAN_CHUNK 1024
#define STAGE_MAX 6144 // per-bin staging cap (ints); bins ~4096 +- 64 here

// ---- per-chunk histogram of dst bins, stored transposed histT[b*C+c] ----
__global__ void k_hist(const int* __restrict__ dst, int E, int C, int NB,
                       int* __restrict__ histT) {
    __shared__ int h[MAXNB];
    int c = blockIdx.x, t = threadIdx.x;
    for (int i = t; i < NB; i += 256) h[i] = 0;
    __syncthreads();
    int base = c * ECHUNK;
    int end = min(base + ECHUNK, E);
    for (int i = base + t; i < end; i += 256)
        atomicAdd(&h[dst[i] >> BINSH], 1);
    __syncthreads();
    for (int b = t; b < NB; b += 256)
        histT[(size_t)b * C + c] = h[b];
}

// ---- generic 3-kernel exclusive scan (in-place safe), L <= 256*SCAN_CHUNK ----
__global__ void k_scan1(const int* __restrict__ in, int L,
                        int* __restrict__ part, int* __restrict__ blocksums) {
    __shared__ int lds[SCAN_CHUNK];
    __shared__ int tsum[256];
    int b = blockIdx.x, t = threadIdx.x;
    int base = b * SCAN_CHUNK;
    for (int i = t; i < SCAN_CHUNK; i += 256)
        lds[i] = (base + i < L) ? in[base + i] : 0;
    __syncthreads();
    int a0 = lds[t*4], a1 = lds[t*4+1], a2 = lds[t*4+2], a3 = lds[t*4+3];
    int ts = a0 + a1 + a2 + a3;
    tsum[t] = ts;
    __syncthreads();
    for (int off = 1; off < 256; off <<= 1) {
        int v = (t >= off) ? tsum[t - off] : 0;
        __syncthreads();
        tsum[t] += v;
        __syncthreads();
    }
    int excl = tsum[t] - ts;
    int i0 = base + t*4;
    if (i0     < L) part[i0]     = excl;
    if (i0 + 1 < L) part[i0 + 1] = excl + a0;
    if (i0 + 2 < L) part[i0 + 2] = excl + a0 + a1;
    if (i0 + 3 < L) part[i0 + 3] = excl + a0 + a1 + a2;
    if (t == 255) blocksums[b] = tsum[255];
}

__global__ void k_scan2(const int* __restrict__ blocksums, int nb, int* __restrict__ blockoff) {
    __shared__ int s[256];
    int t = threadIdx.x;
    s[t] = (t < nb) ? blocksums[t] : 0;
    __syncthreads();
    int mine = s[t];
    for (int off = 1; off < 256; off <<= 1) {
        int v = (t >= off) ? s[t - off] : 0;
        __syncthreads();
        s[t] += v;
        __syncthreads();
    }
    blockoff[t] = s[t] - mine;   // exclusive
}

__global__ void k_scan3f(int* __restrict__ part, const int* __restrict__ blockoff, int L) {
    int i = blockIdx.x * blockDim.x + threadIdx.x;
    if (i < L) part[i] += blockoff[i / SCAN_CHUNK];
}

// ---- scatter edges into bin-grouped bucket; rank via LDS atomic ----
__global__ void k_scatterbin(const int* __restrict__ src, const int* __restrict__ dst,
                             int E, int C, int NB, const int* __restrict__ scanT,
                             int* __restrict__ bucket) {
    __shared__ int cur[MAXNB];
    int c = blockIdx.x, t = threadIdx.x;
    for (int b = t; b < NB; b += 256) cur[b] = scanT[(size_t)b * C + c];
    __syncthreads();
    int base = c * ECHUNK;
    int end = min(base + ECHUNK, E);
    for (int i = base + t; i < end; i += 1024) {
        int i1 = i + 256, i2 = i + 512, i3 = i + 768;
        int d0 = dst[i];
        int d1 = (i1 < end) ? dst[i1] : -1;
        int d2 = (i2 < end) ? dst[i2] : -1;
        int d3 = (i3 < end) ? dst[i3] : -1;
        int s0 = src[i];
        int s1 = (i1 < end) ? src[i1] : 0;
        int s2 = (i2 < end) ? src[i2] : 0;
        int s3 = (i3 < end) ? src[i3] : 0;
        int r0 = atomicAdd(&cur[d0 >> BINSH], 1);
        int r1 = (d1 >= 0) ? atomicAdd(&cur[d1 >> BINSH], 1) : 0;
        int r2 = (d2 >= 0) ? atomicAdd(&cur[d2 >> BINSH], 1) : 0;
        int r3 = (d3 >= 0) ? atomicAdd(&cur[d3 >> BINSH], 1) : 0;
        bucket[r0] = (s0 << BINSH) | (d0 & (BINW - 1));
        if (d1 >= 0) bucket[r1] = (s1 << BINSH) | (d1 & (BINW - 1));
        if (d2 >= 0) bucket[r2] = (s2 << BINSH) | (d2 & (BINW - 1));
        if (d3 >= 0) bucket[r3] = (s3 << BINSH) | (d3 & (BINW - 1));
    }
}

// ---- per-bin CSR finalize: local degree count, scan, staged coalesced write.
//      Produces csr (src grouped by dst), rowptr, dis. No global atomics. ----
__global__ void k_csrbuild(const int* __restrict__ scanT, int C, int NB, int E,
                           const int* __restrict__ bucket, int* __restrict__ csr,
                           int* __restrict__ rowptr, float* __restrict__ dis, int N) {
    __shared__ int cnt[BINW];
    __shared__ int ex[BINW];     // inclusive scan -> derive exclusive
    __shared__ int cur[BINW];
    __shared__ int stage[STAGE_MAX];
    int b = blockIdx.x, t = threadIdx.x;
    int s = scanT[(size_t)b * C];
    int e = (b + 1 < NB) ? scanT[(size_t)(b + 1) * C] : E;
    int len = e - s;
    if (t < BINW) cnt[t] = 0;
    __syncthreads();
    for (int p = s + t; p < e; p += 256)
        atomicAdd(&cnt[bucket[p] & (BINW - 1)], 1);
    __syncthreads();
    if (t < BINW) ex[t] = cnt[t];
    __syncthreads();
    for (int off = 1; off < BINW; off <<= 1) {
        int v = (t < BINW && t >= off) ? ex[t - off] : 0;
        __syncthreads();
        if (t < BINW) ex[t] += v;
        __syncthreads();
    }
    if (t < BINW) {
        int excl = ex[t] - cnt[t];
        cur[t] = excl;
        int n = b * BINW + t;
        if (n <= N) rowptr[n] = s + excl;      // n==N lands here in last bin
        if (n < N)  dis[n] = rsqrtf((float)(cnt[t] + 1));
    }
    __syncthreads();
    if (len <= STAGE_MAX) {
        for (int p = s + t; p < e; p += 256) {
            int w = bucket[p];
            int r = atomicAdd(&cur[w & (BINW - 1)], 1);
            stage[r] = w >> BINSH;
        }
        __syncthreads();
        for (int i = t; i < len; i += 256) csr[s + i] = stage[i];
    } else {
        for (int p = s + t; p < e; p += 256) {
            int w = bucket[p];
            int r = atomicAdd(&cur[w & (BINW - 1)], 1);
            csr[s + r] = w >> BINSH;
        }
    }
}

// ---- g[N,64] = dis[row] * (x[N,11] @ W1[11,64]) ----
__global__ void k_xw1(const float* __restrict__ x, const float* __restrict__ W1,
                      const float* __restrict__ dis, float* __restrict__ g, int N) {
    __shared__ float Ws[INC * HID];
    int t = threadIdx.x;
    for (int i = t; i < INC * HID; i += blockDim.x) Ws[i] = W1[i];
    __syncthreads();
    int c = t & 63;
    for (int row = blockIdx.x * 4 + (t >> 6); row < N; row += gridDim.x * 4) {
        float acc = 0.f;
        #pragma unroll
        for (int k = 0; k < INC; ++k) acc += x[row * INC + k] * Ws[k * HID + c];
        g[row * HID + c] = dis[row] * acc;
    }
}

// ---- g2[N,64] = dis[row] * (a[N,64] @ W2[64,64]), persistent blocks ----
__global__ void k_xw2(const float* __restrict__ in, const float* __restrict__ W2,
                      const float* __restrict__ dis, float* __restrict__ g, int N) {
    __shared__ float Ws[HID * HID];
    int t = threadIdx.x;
    for (int i = t; i < HID * HID; i += blockDim.x) Ws[i] = W2[i];
    __syncthreads();
    int c = t & 63;
    for (int row = blockIdx.x * 4 + (t >> 6); row < N; row += gridDim.x * 4) {
        const float* r = in + row * HID;
        float acc = 0.f;
        #pragma unroll
        for (int k = 0; k < HID; k += 4) {
            float4 rv = *(const float4*)(r + k);
            acc += rv.x * Ws[(k    ) * HID + c];
            acc += rv.y * Ws[(k + 1) * HID + c];
            acc += rv.z * Ws[(k + 2) * HID + c];
            acc += rv.w * Ws[(k + 3) * HID + c];
        }
        g[row * HID + c] = dis[row] * acc;
    }
}

// ---- neighbor-sum core, 8 gathers in flight ----
__device__ __forceinline__ float agg_row(const int* __restrict__ rowptr,
                                         const int* __restrict__ csr,
                                         const float* __restrict__ g,
                                         int row, int lane) {
    int s = rowptr[row], e = rowptr[row + 1];
    float acc = g[(size_t)row * HID + lane];   // self-loop (dis folded in g)
    for (int p = s; p < e; p += 64) {
        int idx = (p + lane < e) ? csr[p + lane] : 0;
        int cnt = min(64, e - p);
        int j = 0;
        for (; j + 7 < cnt; j += 8) {
            int s0 = __shfl(idx, j);
            int s1 = __shfl(idx, j + 1);
            int s2 = __shfl(idx, j + 2);
            int s3 = __shfl(idx, j + 3);
            int s4 = __shfl(idx, j + 4);
            int s5 = __shfl(idx, j + 5);
            int s6 = __shfl(idx, j + 6);
            int s7 = __shfl(idx, j + 7);
            float v0 = g[(size_t)s0 * HID + lane];
            float v1 = g[(size_t)s1 * HID + lane];
            float v2 = g[(size_t)s2 * HID + lane];
            float v3 = g[(size_t)s3 * HID + lane];
            float v4 = g[(size_t)s4 * HID + lane];
            float v5 = g[(size_t)s5 * HID + lane];
            float v6 = g[(size_t)s6 * HID + lane];
            float v7 = g[(size_t)s7 * HID + lane];
            acc += v0; acc += v1; acc += v2; acc += v3;
            acc += v4; acc += v5; acc += v6; acc += v7;
        }
        for (; j < cnt; ++j)
            acc += g[(size_t)__shfl(idx, j) * HID + lane];
    }
    return acc;
}

// ---- layer-1 aggregation: a[row] = relu(dis[row]*sum + b) ----
__global__ void k_agg1(const int* __restrict__ rowptr, const int* __restrict__ csr,
                       const float* __restrict__ g, const float* __restrict__ dis,
                       const float* __restrict__ b, float* __restrict__ outA, int N) {
    int lane = threadIdx.x & 63;
    int row = (blockIdx.x * blockDim.x + threadIdx.x) >> 6;
    if (row >= N) return;
    float acc = agg_row(rowptr, csr, g, row, lane);
    float v = dis[row] * acc + b[lane];
    outA[(size_t)row * HID + lane] = v > 0.f ? v : 0.f;
}

// ---- layer-2 aggregation fused with head ----
__global__ void k_agg2_head(const int* __restrict__ rowptr, const int* __restrict__ csr,
                            const float* __restrict__ g, const float* __restrict__ dis,
                            const float* __restrict__ b, const float* __restrict__ Wl,
                            const float* __restrict__ bl, float* __restrict__ out, int N) {
    int lane = threadIdx.x & 63;
    int row = (blockIdx.x * blockDim.x + threadIdx.x) >> 6;
    if (row >= N) return;
    float acc = agg_row(rowptr, csr, g, row, lane);
    float v = dis[row] * acc + b[lane];
    v = v > 0.f ? v : 0.f;
    v *= Wl[lane];
    #pragma unroll
    for (int off = 32; off > 0; off >>= 1) v += __shfl_down(v, off);
    if (lane == 0) out[row] = v + bl[0];
}

extern "C" void kernel_launch(void* const* d_in, const int* in_sizes, int n_in,
                              void* d_out, int out_size, void* d_ws, size_t ws_size,
                              hipStream_t stream) {
    const float* x  = (const float*)d_in[0];
    const int*   ei = (const int*)d_in[1];
    const float* W1 = (const float*)d_in[2];
    const float* b1 = (const float*)d_in[3];
    const float* W2 = (const float*)d_in[4];
    const float* b2 = (const float*)d_in[5];
    const float* Wl = (const float*)d_in[6];
    const float* bl = (const float*)d_in[7];
    float* out = (float*)d_out;

    const int N = in_sizes[0] / INC;    // 100000
    const int E = in_sizes[1] / 2;      // 3200000
    const int NB = (N + BINW - 1) / BINW;        // 782
    const int C  = (E + ECHUNK - 1) / ECHUNK;    // 196
    const int L  = NB * C;                        // 153272
    const int nScan = (L + SCAN_CHUNK - 1) / SCAN_CHUNK;  // 150 (<=256)

    char* ws = (char*)d_ws;
    size_t off = 0;
    auto alloc = [&](size_t bytes) { void* p = ws + off; off += (bytes + 255) / 256 * 256; return p; };
    int*   histT    = (int*)alloc((size_t)L * 4);     // scanned in place
    int*   blocksums= (int*)alloc(256 * 4);
    int*   blockoff = (int*)alloc(256 * 4);
    int*   rowptr   = (int*)alloc((size_t)(N + 1) * 4);
    float* dis      = (float*)alloc((size_t)N * 4);
    int*   csr      = (int*)alloc((size_t)E * 4);
    float* bufG     = (float*)alloc((size_t)N * HID * 4);
    float* bufA     = (float*)alloc((size_t)N * HID * 4);
    // bucket (E ints = 12.8 MB) aliases bufA: bucket's last read (k_csrbuild)
    // precedes bufA's first write (k_agg1).
    int* bucket = (int*)bufA;

    const int TPB = 256;
    const int* esrc = ei;
    const int* edst = ei + E;
    const int waveBlocks = ((size_t)N * 64 + TPB - 1) / TPB;   // wave per row

    // CSR build — zero global atomics
    k_hist<<<C, TPB, 0, stream>>>(edst, E, C, NB, histT);
    k_scan1<<<nScan, TPB, 0, stream>>>(histT, L, histT, blocksums);
    k_scan2<<<1, TPB, 0, stream>>>(blocksums, nScan, blockoff);
    k_scan3f<<<(L + TPB - 1) / TPB, TPB, 0, stream>>>(histT, blockoff, L);
    k_scatterbin<<<C, TPB, 0, stream>>>(esrc, edst, E, C, NB, histT, bucket);
    k_csrbuild<<<NB, TPB, 0, stream>>>(histT, C, NB, E, bucket, csr, rowptr, dis, N);

    // layer 1
    k_xw1<<<2048, TPB, 0, stream>>>(x, W1, dis, bufG, N);
    k_agg1<<<waveBlocks, TPB, 0, stream>>>(rowptr, csr, bufG, dis, b1, bufA, N);

    // layer 2 (+ fused head)
    k_xw2<<<2048, TPB, 0, stream>>>(bufA, W2, dis, bufG, N);
    k_agg2_head<<<waveBlocks, TPB, 0, stream>>>(rowptr, csr, bufG, dis, b2, Wl, bl, out, N);
}

// Round 9
// 305.988 us; speedup vs baseline: 1.8815x; 1.1523x over previous
//
#include <hip/hip_runtime.h>

// GCN 2-layer + head.
// R9: R8 structure + (a) xw2 fused into agg1 epilogue (W2 in LDS, per-wave
//     arow matvec -> writes g2 directly, no bufA round-trip), (b) build chain
//     parallelized: ECHUNK 8192 (391 chunks), int4 edge loads, 8 LDS-atomic
//     chains in scatterbin, scan2 widened to 512 threads.
// bucket word = (src<<7) | (dst&127), src < 2^17 so fits in 24 bits.

#define HID 64
#define INC 11
#define BINSH 7
#define BINW 128
#define MAXNB 800      // >= ceil(100000/128)=782
#define ECHUNK 8192
#define SCAN_CHUNK 1024
#define STAGE_MAX 6144 // per-bin staging cap (ints); bins ~4096 +- 5sigma here

// ---- per-chunk histogram of dst bins, stored transposed histT[b*C+c] ----
__global__ void k_hist(const int* __restrict__ dst, int E, int C, int NB,
                       int* __restrict__ histT) {
    __shared__ int h[MAXNB];
    int c = blockIdx.x, t = threadIdx.x;
    for (int i = t; i < NB; i += 256) h[i] = 0;
    __syncthreads();
    int base = c * ECHUNK;
    int end = min(base + ECHUNK, E);
    int n4 = (end - base) >> 2;            // E%4==0, base%4==0
    const int4* d4 = (const int4*)(dst + base);
    for (int i = t; i < n4; i += 256) {
        int4 d = d4[i];
        atomicAdd(&h[d.x >> BINSH], 1);
        atomicAdd(&h[d.y >> BINSH], 1);
        atomicAdd(&h[d.z >> BINSH], 1);
        atomicAdd(&h[d.w >> BINSH], 1);
    }
    __syncthreads();
    for (int b = t; b < NB; b += 256)
        histT[(size_t)b * C + c] = h[b];
}

// ---- generic 3-kernel exclusive scan (in-place safe), L <= 512*SCAN_CHUNK ----
__global__ void k_scan1(const int* __restrict__ in, int L,
                        int* __restrict__ part, int* __restrict__ blocksums) {
    __shared__ int lds[SCAN_CHUNK];
    __shared__ int tsum[256];
    int b = blockIdx.x, t = threadIdx.x;
    int base = b * SCAN_CHUNK;
    for (int i = t; i < SCAN_CHUNK; i += 256)
        lds[i] = (base + i < L) ? in[base + i] : 0;
    __syncthreads();
    int a0 = lds[t*4], a1 = lds[t*4+1], a2 = lds[t*4+2], a3 = lds[t*4+3];
    int ts = a0 + a1 + a2 + a3;
    tsum[t] = ts;
    __syncthreads();
    for (int off = 1; off < 256; off <<= 1) {
        int v = (t >= off) ? tsum[t - off] : 0;
        __syncthreads();
        tsum[t] += v;
        __syncthreads();
    }
    int excl = tsum[t] - ts;
    int i0 = base + t*4;
    if (i0     < L) part[i0]     = excl;
    if (i0 + 1 < L) part[i0 + 1] = excl + a0;
    if (i0 + 2 < L) part[i0 + 2] = excl + a0 + a1;
    if (i0 + 3 < L) part[i0 + 3] = excl + a0 + a1 + a2;
    if (t == 255) blocksums[b] = tsum[255];
}

__global__ void k_scan2(const int* __restrict__ blocksums, int nb, int* __restrict__ blockoff) {
    __shared__ int s[512];
    int t = threadIdx.x;    // 512 threads
    s[t] = (t < nb) ? blocksums[t] : 0;
    __syncthreads();
    int mine = s[t];
    for (int off = 1; off < 512; off <<= 1) {
        int v = (t >= off) ? s[t - off] : 0;
        __syncthreads();
        s[t] += v;
        __syncthreads();
    }
    blockoff[t] = s[t] - mine;   // exclusive
}

__global__ void k_scan3f(int* __restrict__ part, const int* __restrict__ blockoff, int L) {
    int i = blockIdx.x * blockDim.x + threadIdx.x;
    if (i < L) part[i] += blockoff[i / SCAN_CHUNK];
}

// ---- scatter edges into bin-grouped bucket; rank via LDS atomic, 8 chains ----
__global__ void k_scatterbin(const int* __restrict__ src, const int* __restrict__ dst,
                             int E, int C, int NB, const int* __restrict__ scanT,
                             int* __restrict__ bucket) {
    __shared__ int cur[MAXNB];
    int c = blockIdx.x, t = threadIdx.x;
    for (int b = t; b < NB; b += 256) cur[b] = scanT[(size_t)b * C + c];
    __syncthreads();
    int base = c * ECHUNK;
    int end = min(base + ECHUNK, E);
    int n4 = (end - base) >> 2;            // E%4==0, base%4==0
    const int4* d4 = (const int4*)(dst + base);
    const int4* s4 = (const int4*)(src + base);
    for (int i = t; i < n4; i += 512) {
        int4 da = d4[i], sa = s4[i];
        bool hb = (i + 256) < n4;
        int4 db, sb;
        if (hb) { db = d4[i + 256]; sb = s4[i + 256]; }
        int r0 = atomicAdd(&cur[da.x >> BINSH], 1);
        int r1 = atomicAdd(&cur[da.y >> BINSH], 1);
        int r2 = atomicAdd(&cur[da.z >> BINSH], 1);
        int r3 = atomicAdd(&cur[da.w >> BINSH], 1);
        int r4 = 0, r5 = 0, r6 = 0, r7 = 0;
        if (hb) {
            r4 = atomicAdd(&cur[db.x >> BINSH], 1);
            r5 = atomicAdd(&cur[db.y >> BINSH], 1);
            r6 = atomicAdd(&cur[db.z >> BINSH], 1);
            r7 = atomicAdd(&cur[db.w >> BINSH], 1);
        }
        bucket[r0] = (sa.x << BINSH) | (da.x & (BINW - 1));
        bucket[r1] = (sa.y << BINSH) | (da.y & (BINW - 1));
        bucket[r2] = (sa.z << BINSH) | (da.z & (BINW - 1));
        bucket[r3] = (sa.w << BINSH) | (da.w & (BINW - 1));
        if (hb) {
            bucket[r4] = (sb.x << BINSH) | (db.x & (BINW - 1));
            bucket[r5] = (sb.y << BINSH) | (db.y & (BINW - 1));
            bucket[r6] = (sb.z << BINSH) | (db.z & (BINW - 1));
            bucket[r7] = (sb.w << BINSH) | (db.w & (BINW - 1));
        }
    }
}

// ---- per-bin CSR finalize: local degree count, scan, staged coalesced write.
//      Produces csr (src grouped by dst), rowptr, dis. No global atomics. ----
__global__ void k_csrbuild(const int* __restrict__ scanT, int C, int NB, int E,
                           const int* __restrict__ bucket, int* __restrict__ csr,
                           int* __restrict__ rowptr, float* __restrict__ dis, int N) {
    __shared__ int cnt[BINW];
    __shared__ int ex[BINW];     // inclusive scan -> derive exclusive
    __shared__ int cur[BINW];
    __shared__ int stage[STAGE_MAX];
    int b = blockIdx.x, t = threadIdx.x;
    int s = scanT[(size_t)b * C];
    int e = (b + 1 < NB) ? scanT[(size_t)(b + 1) * C] : E;
    int len = e - s;
    if (t < BINW) cnt[t] = 0;
    __syncthreads();
    for (int p = s + t; p < e; p += 256)
        atomicAdd(&cnt[bucket[p] & (BINW - 1)], 1);
    __syncthreads();
    if (t < BINW) ex[t] = cnt[t];
    __syncthreads();
    for (int off = 1; off < BINW; off <<= 1) {
        int v = (t < BINW && t >= off) ? ex[t - off] : 0;
        __syncthreads();
        if (t < BINW) ex[t] += v;
        __syncthreads();
    }
    if (t < BINW) {
        int excl = ex[t] - cnt[t];
        cur[t] = excl;
        int n = b * BINW + t;
        if (n <= N) rowptr[n] = s + excl;      // n==N lands here in last bin
        if (n < N)  dis[n] = rsqrtf((float)(cnt[t] + 1));
    }
    __syncthreads();
    if (len <= STAGE_MAX) {
        for (int p = s + t; p < e; p += 256) {
            int w = bucket[p];
            int r = atomicAdd(&cur[w & (BINW - 1)], 1);
            stage[r] = w >> BINSH;
        }
        __syncthreads();
        for (int i = t; i < len; i += 256) csr[s + i] = stage[i];
    } else {
        for (int p = s + t; p < e; p += 256) {
            int w = bucket[p];
            int r = atomicAdd(&cur[w & (BINW - 1)], 1);
            csr[s + r] = w >> BINSH;
        }
    }
}

// ---- g1[N,64] = dis[row] * (x[N,11] @ W1[11,64]) ----
__global__ void k_xw1(const float* __restrict__ x, const float* __restrict__ W1,
                      const float* __restrict__ dis, float* __restrict__ g, int N) {
    __shared__ float Ws[INC * HID];
    int t = threadIdx.x;
    for (int i = t; i < INC * HID; i += blockDim.x) Ws[i] = W1[i];
    __syncthreads();
    int c = t & 63;
    for (int row = blockIdx.x * 4 + (t >> 6); row < N; row += gridDim.x * 4) {
        float acc = 0.f;
        #pragma unroll
        for (int k = 0; k < INC; ++k) acc += x[row * INC + k] * Ws[k * HID + c];
        g[row * HID + c] = dis[row] * acc;
    }
}

// ---- neighbor-sum core, 8 gathers in flight ----
__device__ __forceinline__ float agg_row(const int* __restrict__ rowptr,
                                         const int* __restrict__ csr,
                                         const float* __restrict__ g,
                                         int row, int lane) {
    int s = rowptr[row], e = rowptr[row + 1];
    float acc = g[(size_t)row * HID + lane];   // self-loop (dis folded in g)
    for (int p = s; p < e; p += 64) {
        int idx = (p + lane < e) ? csr[p + lane] : 0;
        int cnt = min(64, e - p);
        int j = 0;
        for (; j + 7 < cnt; j += 8) {
            int s0 = __shfl(idx, j);
            int s1 = __shfl(idx, j + 1);
            int s2 = __shfl(idx, j + 2);
            int s3 = __shfl(idx, j + 3);
            int s4 = __shfl(idx, j + 4);
            int s5 = __shfl(idx, j + 5);
            int s6 = __shfl(idx, j + 6);
            int s7 = __shfl(idx, j + 7);
            float v0 = g[(size_t)s0 * HID + lane];
            float v1 = g[(size_t)s1 * HID + lane];
            float v2 = g[(size_t)s2 * HID + lane];
            float v3 = g[(size_t)s3 * HID + lane];
            float v4 = g[(size_t)s4 * HID + lane];
            float v5 = g[(size_t)s5 * HID + lane];
            float v6 = g[(size_t)s6 * HID + lane];
            float v7 = g[(size_t)s7 * HID + lane];
            acc += v0; acc += v1; acc += v2; acc += v3;
            acc += v4; acc += v5; acc += v6; acc += v7;
        }
        for (; j < cnt; ++j)
            acc += g[(size_t)__shfl(idx, j) * HID + lane];
    }
    return acc;
}

// ---- layer-1 aggregation fused with xw2:
//      a = relu(dis*sum + b1);  g2[row] = dis[row] * (a @ W2) ----
__global__ void k_agg1_xw2(const int* __restrict__ rowptr, const int* __restrict__ csr,
                           const float* __restrict__ g, const float* __restrict__ dis,
                           const float* __restrict__ b1, const float* __restrict__ W2,
                           float* __restrict__ g2, int N) {
    __shared__ float W2s[HID * HID];   // 16 KB
    __shared__ float arow[4][HID];     // per-wave row buffer (no cross-wave use)
    int t = threadIdx.x;
    for (int i = t; i < HID * HID; i += 256) W2s[i] = W2[i];
    __syncthreads();
    int lane = t & 63, wv = t >> 6;
    int row = (blockIdx.x * blockDim.x + t) >> 6;
    if (row >= N) return;              // grid sized exactly: never taken at N=100k
    float acc = agg_row(rowptr, csr, g, row, lane);
    float v = dis[row] * acc + b1[lane];
    v = v > 0.f ? v : 0.f;             // a[row][lane]
    arow[wv][lane] = v;                // wave-internal exchange; lgkmcnt orders it
    float acc2 = 0.f;
    #pragma unroll
    for (int k = 0; k < HID; k += 4) {
        float a0 = arow[wv][k], a1 = arow[wv][k+1], a2 = arow[wv][k+2], a3 = arow[wv][k+3];
        acc2 += a0 * W2s[(k    ) * HID + lane];
        acc2 += a1 * W2s[(k + 1) * HID + lane];
        acc2 += a2 * W2s[(k + 2) * HID + lane];
        acc2 += a3 * W2s[(k + 3) * HID + lane];
    }
    g2[(size_t)row * HID + lane] = dis[row] * acc2;
}

// ---- layer-2 aggregation fused with head ----
__global__ void k_agg2_head(const int* __restrict__ rowptr, const int* __restrict__ csr,
                            const float* __restrict__ g, const float* __restrict__ dis,
                            const float* __restrict__ b, const float* __restrict__ Wl,
                            const float* __restrict__ bl, float* __restrict__ out, int N) {
    int lane = threadIdx.x & 63;
    int row = (blockIdx.x * blockDim.x + threadIdx.x) >> 6;
    if (row >= N) return;
    float acc = agg_row(rowptr, csr, g, row, lane);
    float v = dis[row] * acc + b[lane];
    v = v > 0.f ? v : 0.f;
    v *= Wl[lane];
    #pragma unroll
    for (int off = 32; off > 0; off >>= 1) v += __shfl_down(v, off);
    if (lane == 0) out[row] = v + bl[0];
}

extern "C" void kernel_launch(void* const* d_in, const int* in_sizes, int n_in,
                              void* d_out, int out_size, void* d_ws, size_t ws_size,
                              hipStream_t stream) {
    const float* x  = (const float*)d_in[0];
    const int*   ei = (const int*)d_in[1];
    const float* W1 = (const float*)d_in[2];
    const float* b1 = (const float*)d_in[3];
    const float* W2 = (const float*)d_in[4];
    const float* b2 = (const float*)d_in[5];
    const float* Wl = (const float*)d_in[6];
    const float* bl = (const float*)d_in[7];
    float* out = (float*)d_out;

    const int N = in_sizes[0] / INC;    // 100000
    const int E = in_sizes[1] / 2;      // 3200000
    const int NB = (N + BINW - 1) / BINW;        // 782
    const int C  = (E + ECHUNK - 1) / ECHUNK;    // 391
    const int L  = NB * C;                        // 305762
    const int nScan = (L + SCAN_CHUNK - 1) / SCAN_CHUNK;  // 299 (<=512)

    char* ws = (char*)d_ws;
    size_t off = 0;
    auto alloc = [&](size_t bytes) { void* p = ws + off; off += (bytes + 255) / 256 * 256; return p; };
    int*   histT    = (int*)alloc((size_t)L * 4);     // scanned in place
    int*   blocksums= (int*)alloc(512 * 4);
    int*   blockoff = (int*)alloc(512 * 4);
    int*   rowptr   = (int*)alloc((size_t)(N + 1) * 4);
    float* dis      = (float*)alloc((size_t)N * 4);
    int*   csr      = (int*)alloc((size_t)E * 4);
    float* bufG1    = (float*)alloc((size_t)N * HID * 4);
    float* bufG2    = (float*)alloc((size_t)N * HID * 4);
    // bucket (E ints = 12.8 MB) aliases bufG1: bucket's last read (k_csrbuild)
    // precedes bufG1's first write (k_xw1).
    int* bucket = (int*)bufG1;

    const int TPB = 256;
    const int* esrc = ei;
    const int* edst = ei + E;
    const int waveBlocks = ((size_t)N * 64 + TPB - 1) / TPB;   // wave per row

    // CSR build — zero global atomics
    k_hist<<<C, TPB, 0, stream>>>(edst, E, C, NB, histT);
    k_scan1<<<nScan, TPB, 0, stream>>>(histT, L, histT, blocksums);
    k_scan2<<<1, 512, 0, stream>>>(blocksums, nScan, blockoff);
    k_scan3f<<<(L + TPB - 1) / TPB, TPB, 0, stream>>>(histT, blockoff, L);
    k_scatterbin<<<C, TPB, 0, stream>>>(esrc, edst, E, C, NB, histT, bucket);
    k_csrbuild<<<NB, TPB, 0, stream>>>(histT, C, NB, E, bucket, csr, rowptr, dis, N);

    // layer 1 (+ fused xw2)
    k_xw1<<<2048, TPB, 0, stream>>>(x, W1, dis, bufG1, N);
    k_agg1_xw2<<<waveBlocks, TPB, 0, stream>>>(rowptr, csr, bufG1, dis, b1, W2, bufG2, N);

    // layer 2 (+ fused head)
    k_agg2_head<<<waveBlocks, TPB, 0, stream>>>(rowptr, csr, bufG2, dis, b2, Wl, bl, out, N);
}